// Round 5
// baseline (65.725 us; speedup 1.0000x reference)
//
#include <hip/hip_runtime.h>
#include <math.h>

// Problem constants (match reference)
#define BN 32
#define RR 13
#define CC 13
#define AA 5
#define KK 20
#define CELLSZ 25
#define NN (RR * CC * AA)      // 845 cells per batch
#define TOT (NN * CELLSZ)
#define THRESH 0.5f
#define NMS_TH 0.4f

// ws: fixed-slot candidate records, one per (b,n) cell, 8 floats = 32 B:
//   { p, km(as int bits), x1, y1, x2, y2, area, 0 }
// Every slot is written every call -> no counter init, no memset dispatch.

__device__ __forceinline__ float sigmoidf_(float x) {
    return 1.0f / (1.0f + expf(-x));
}

// One thread per (b,n) cell. Writes 25 output floats (boxes/obj + zero
// scores) and its 32 B record. No atomics.
__global__ __launch_bounds__(256) void decode_kernel(
        const float* __restrict__ x,
        const float* __restrict__ bias,
        float* __restrict__ out,
        float4* __restrict__ recs) {
    int idx = blockIdx.x * 256 + threadIdx.x;
    if (idx >= BN * NN) return;
    int n   = idx % NN;
    int r   = n / (CC * AA);
    int rem = n - r * (CC * AA);
    int c   = rem / AA;
    int a   = rem - c * AA;

    const float* t = x + (size_t)idx * CELLSZ;

    float bx  = (sigmoidf_(t[0]) + (float)c) / (float)CC;
    float by  = (sigmoidf_(t[1]) + (float)r) / (float)RR;
    float bw  = expf(t[2]) * bias[2 * a]     / (float)RR;
    float bh  = expf(t[3]) * bias[2 * a + 1] / (float)CC;
    float obj = sigmoidf_(t[4]);

    float l[KK];
    float m = t[5];
#pragma unroll
    for (int k = 0; k < KK; ++k) { l[k] = t[5 + k]; m = fmaxf(m, l[k]); }
    float s = 0.f;
#pragma unroll
    for (int k = 0; k < KK; ++k) s += expf(l[k] - m);
    int km = 0;
#pragma unroll
    for (int k = 1; k < KK; ++k) if (l[k] > l[km]) km = k;

    // Only the argmax class can exceed 0.5 (softmax sums to 1, obj < 1);
    // expf(0) == 1 exactly so p is bitwise the reference's obj*(e[km]/s).
    float p = obj * (1.0f / s);

    float* o = out + (size_t)idx * CELLSZ;
    o[0] = bx; o[1] = by; o[2] = bw; o[3] = bh; o[4] = obj;
#pragma unroll
    for (int k = 0; k < KK; ++k) o[5 + k] = 0.f;   // kept scores patched by NMS

    float x1 = bx - bw * 0.5f, y1 = by - bh * 0.5f;
    recs[(size_t)idx * 2]     = make_float4(p, __int_as_float(km), x1, y1);
    recs[(size_t)idx * 2 + 1] = make_float4(x1 + bw, y1 + bh, bw * bh, 0.f);
}

// One block per batch (16 waves). Compact candidates into an LDS pool, then
// each wave greedily NMS-es its classes (k = wave, wave+16) and patches kept
// scores into out. Tie-break (score desc, n asc) == reference stable argsort.
__global__ __launch_bounds__(1024) void nms_kernel(
        const float4* __restrict__ recs,
        float* __restrict__ out) {
    __shared__ int   pcnt;
    __shared__ int   ctag[NN], cidx[NN];
    __shared__ float csc[NN], px1[NN], py1[NN], px2[NN], py2[NN], par[NN];

    const int b    = blockIdx.x;
    const int tid  = threadIdx.x;
    const int lane = tid & 63;
    const int wave = tid >> 6;

    if (tid == 0) pcnt = 0;
    __syncthreads();

    if (tid < NN) {
        float4 r0 = recs[((size_t)b * NN + tid) * 2];
        if (r0.x > THRESH) {
            float4 r1 = recs[((size_t)b * NN + tid) * 2 + 1];
            int slot = atomicAdd(&pcnt, 1);            // LDS atomic, rare
            ctag[slot] = __float_as_int(r0.y);
            cidx[slot] = tid;
            csc[slot]  = r0.x;
            px1[slot]  = r0.z;  py1[slot] = r0.w;
            px2[slot]  = r1.x;  py2[slot] = r1.y;
            par[slot]  = r1.z;
        }
    }
    __syncthreads();

    const int mtot = pcnt;
    if (mtot == 0) return;
    const int T = (mtot + 63) >> 6;                    // pool slots/lane (<=14)

    for (int k = wave; k < KK; k += 16) {
        unsigned alive = 0;
        for (int tt = 0; tt < T; ++tt) {
            int j = lane + (tt << 6);
            if (j < mtot && ctag[j] == k) alive |= (1u << tt);
        }
        while (true) {
            float bs = -1.f; int bnn = 0x7fffffff; int bg = -1;
            for (int tt = 0; tt < T; ++tt) {
                if ((alive >> tt) & 1u) {
                    int j = lane + (tt << 6);
                    float sc = csc[j]; int nn = cidx[j];
                    if (sc > bs || (sc == bs && nn < bnn)) { bs = sc; bnn = nn; bg = j; }
                }
            }
#pragma unroll
            for (int off = 32; off; off >>= 1) {       // wave butterfly argmax
                float os = __shfl_xor(bs, off);
                int   on = __shfl_xor(bnn, off);
                int   og = __shfl_xor(bg, off);
                if (os > bs || (os == bs && on < bnn)) { bs = os; bnn = on; bg = og; }
            }
            if (bg < 0) break;                         // nothing alive (uniform)

            float X1 = px1[bg], Y1 = py1[bg], X2 = px2[bg], Y2 = py2[bg], AR = par[bg];
            if ((bg & 63) == lane) {                   // owner keeps winner
                out[((size_t)b * NN + bnn) * CELLSZ + 5 + k] = bs;
                alive &= ~(1u << (bg >> 6));
            }
            for (int tt = 0; tt < T; ++tt) {           // suppress overlaps
                int j = lane + (tt << 6);
                if (((alive >> tt) & 1u) && j != bg) {
                    float iw = fmaxf(0.f, fminf(X2, px2[j]) - fmaxf(X1, px1[j]));
                    float ih = fmaxf(0.f, fminf(Y2, py2[j]) - fmaxf(Y1, py1[j]));
                    float inter = iw * ih;
                    float uni   = AR + par[j] - inter;
                    if (inter / fmaxf(uni, 1e-9f) > NMS_TH) alive &= ~(1u << tt);
                }
            }
        }
    }
}

extern "C" void kernel_launch(void* const* d_in, const int* in_sizes, int n_in,
                              void* d_out, int out_size, void* d_ws, size_t ws_size,
                              hipStream_t stream) {
    const float* x    = (const float*)d_in[0];
    const float* bias = (const float*)d_in[1];
    float*  out  = (float*)d_out;
    float4* recs = (float4*)d_ws;    // BN*NN*32 B = 865 KB << ws_size

    decode_kernel<<<(BN * NN + 255) / 256, 256, 0, stream>>>(x, bias, out, recs);
    nms_kernel<<<BN, 1024, 0, stream>>>(recs, out);
}